// Round 2
// baseline (294.768 us; speedup 1.0000x reference)
//
#include <hip/hip_runtime.h>
#include <hip/hip_bf16.h>
#include <math.h>

// Problem constants (match reference)
#define BATCH   131072
#define FEAT    256
#define NCLASS  50000
#define EPS     1e-12f
#define LAMBDA  0.5f
#define CAP     32      // fallback-path bucket capacity

constexpr int WPB     = 4;                    // waves per 256-thread block
constexpr int NBLK_NS = BATCH  / WPB;         // 32768 (norm pass blocks)
constexpr int NBLK_SS = NCLASS / WPB;         // 12500
constexpr int NSCAN   = (NCLASS + 255) / 256; // 196

// Fast-path ws layout (4B units):
//   cnt[NCLASS] | cursor[NCLASS] | bsum[256] | boff[256]
//   | pA[NBLK_NS] | pB[NBLK_SS] | sIdx[BATCH] | rinvS[BATCH]
// d_out: out[0]=loss ; out[1..] = new_centers.
//
// v3 design: the gather kernel was dependency-chain bound (butterfly norm
// reduction inside the gather loop -> 21% HBM BW). Norms now computed in a
// streaming pass (latency hidden by 131K independent rows) and written in
// SORTED SLOT ORDER, so the gather loop is pure shfl->load->fma with 8 rows
// in flight and zero cross-lane reductions.

__device__ __forceinline__ float wave_reduce_sum(float v) {
    #pragma unroll
    for (int m = 32; m; m >>= 1) v += __shfl_xor(v, m, 64);
    return v;
}

// ---- histogram ----
__global__ __launch_bounds__(256) void histo(const int* __restrict__ labels,
                                             int* __restrict__ cnt) {
    const int i = blockIdx.x * 256 + threadIdx.x;
    atomicAdd(&cnt[labels[i]], 1);
}

// ---- multi-block exclusive scan of cnt -> cursor ----
__global__ __launch_bounds__(256) void scan_bsum(const int* __restrict__ cnt,
                                                 int* __restrict__ bsum) {
    __shared__ int s[256];
    const int i = blockIdx.x * 256 + threadIdx.x;
    s[threadIdx.x] = (i < NCLASS) ? cnt[i] : 0;
    __syncthreads();
    for (int off = 128; off; off >>= 1) {
        if (threadIdx.x < off) s[threadIdx.x] += s[threadIdx.x + off];
        __syncthreads();
    }
    if (threadIdx.x == 0) bsum[blockIdx.x] = s[0];
}

__global__ __launch_bounds__(256) void scan_boff(const int* __restrict__ bsum,
                                                 int* __restrict__ boff) {
    __shared__ int s[256];
    const int t = threadIdx.x;
    const int v = (t < NSCAN) ? bsum[t] : 0;
    s[t] = v;
    __syncthreads();
    for (int off = 1; off < 256; off <<= 1) {
        int u = (t >= off) ? s[t - off] : 0;
        __syncthreads();
        s[t] += u;
        __syncthreads();
    }
    if (t < NSCAN) boff[t] = s[t] - v;
}

__global__ __launch_bounds__(256) void scan_final(const int* __restrict__ cnt,
                                                  const int* __restrict__ boff,
                                                  int* __restrict__ cursor) {
    __shared__ int s[256];
    const int t = threadIdx.x;
    const int i = blockIdx.x * 256 + t;
    const int v = (i < NCLASS) ? cnt[i] : 0;
    s[t] = v;
    __syncthreads();
    for (int off = 1; off < 256; off <<= 1) {
        int u = (t >= off) ? s[t - off] : 0;
        __syncthreads();
        s[t] += u;
        __syncthreads();
    }
    if (i < NCLASS) cursor[i] = s[t] - v + boff[blockIdx.x];
}

// ---- streaming norm + index/rinv scatter (fused) ----
// Per wave: one row. Butterfly norm latency is hidden by 131072 independent
// rows. Writes sIdx[slot]=row and rinvS[slot]=rinv so the gather kernel can
// read both coalesced. Also emits the sum ||f||^2 loss partial (pA).
__global__ __launch_bounds__(256) void norm_scatter(
        const float* __restrict__ feat,
        const int*   __restrict__ labels,
        int*         __restrict__ cursor,   // advanced to end offsets
        int*         __restrict__ sIdx,
        float*       __restrict__ rinvS,
        float*       __restrict__ pA) {
    const int wave = threadIdx.x >> 6;
    const int lane = threadIdx.x & 63;
    const int row  = blockIdx.x * WPB + wave;   // linear -> coalesced read

    const float4 v = ((const float4*)(feat + (size_t)row * FEAT))[lane];
    const float ss = wave_reduce_sum(v.x*v.x + v.y*v.y + v.z*v.z + v.w*v.w);
    const float rinv = 1.0f / fmaxf(sqrtf(ss), EPS);

    if (lane == 0) {
        const int slot = atomicAdd(&cursor[labels[row]], 1);
        sIdx[slot]  = row;
        rinvS[slot] = rinv;
    }

    __shared__ float red[WPB];
    if (lane == 0) red[wave] = ss * rinv * rinv;   // ||f||^2 after normalize
    __syncthreads();
    if (threadIdx.x == 0)
        pA[blockIdx.x] = red[0] + red[1] + red[2] + red[3];
}

// ---- gather + segmented sum + center update + loss partial ----
// Inner loop: shfl(idx), shfl(rv) -> float4 load -> fma. No cross-lane
// reductions, no guards (padded lanes have rv=0, idx=0 -> row-0 L1-hot
// loads contributing exactly 0). 8 loads in flight per wave.
__global__ __launch_bounds__(256) void segsum_gather2(
        const float* __restrict__ feat,
        const float* __restrict__ centers,
        const int*   __restrict__ cnt,
        const int*   __restrict__ cursor_end,   // end offsets (post-scatter)
        const int*   __restrict__ sIdx,
        const float* __restrict__ rinvS,
        float*       __restrict__ outc,         // = out+1
        float*       __restrict__ pB) {
    const int wave = threadIdx.x >> 6;
    const int lane = threadIdx.x & 63;
    const int c    = blockIdx.x * WPB + wave;   // < NCLASS exactly

    const int n     = cnt[c];
    const int start = cursor_end[c] - n;

    float4 acc = {0.f, 0.f, 0.f, 0.f};

    for (int base = 0; base < n; base += 64) {
        const int cn = min(64, n - base);
        int   myidx = 0;
        float myrv  = 0.f;
        if (lane < cn) {
            myidx = sIdx [start + base + lane];
            myrv  = rinvS[start + base + lane];
        }

        for (int s = 0; s < cn; s += 8) {
            #pragma unroll
            for (int k = 0; k < 8; ++k) {
                const int   r  = __shfl(myidx, s + k, 64);
                const float rv = __shfl(myrv,  s + k, 64);
                const float4 v = ((const float4*)(feat + (size_t)r * FEAT))[lane];
                acc.x += v.x * rv;
                acc.y += v.y * rv;
                acc.z += v.z * rv;
                acc.w += v.w * rv;
            }
        }
    }

    const float4 cv = ((const float4*)(centers + (size_t)c * FEAT))[lane];
    const float fn = (float)n;
    const float w  = 1.0f / (1.0f + fn);

    float4 nc;
    nc.x = cv.x - LAMBDA * (fn * cv.x - acc.x) * w;
    nc.y = cv.y - LAMBDA * (fn * cv.y - acc.y) * w;
    nc.z = cv.z - LAMBDA * (fn * cv.z - acc.z) * w;
    nc.w = cv.w - LAMBDA * (fn * cv.w - acc.w) * w;
    ((float4*)(outc + (size_t)c * FEAT))[lane] = nc;

    // loss partial: n*||c||^2 - 2*acc.c  (sum ||f||^2 comes from pA)
    float lp = fn * (cv.x*cv.x + cv.y*cv.y + cv.z*cv.z + cv.w*cv.w)
             - 2.0f * (acc.x*cv.x + acc.y*cv.y + acc.z*cv.z + acc.w*cv.w);
    lp = wave_reduce_sum(lp);

    __shared__ float red[WPB];
    if (lane == 0) red[wave] = lp;
    __syncthreads();
    if (threadIdx.x == 0)
        pB[blockIdx.x] = red[0] + red[1] + red[2] + red[3];
}

// ---- final loss reduction ----
__global__ __launch_bounds__(1024) void finish(const float* __restrict__ pA,
                                               const float* __restrict__ pB,
                                               float* __restrict__ out0) {
    float s = 0.0f;
    for (int i = threadIdx.x; i < NBLK_NS; i += 1024) s += pA[i];
    for (int i = threadIdx.x; i < NBLK_SS; i += 1024) s += pB[i];
    s = wave_reduce_sum(s);
    __shared__ float red[16];
    const int wave = threadIdx.x >> 6;
    const int lane = threadIdx.x & 63;
    if (lane == 0) red[wave] = s;
    __syncthreads();
    if (threadIdx.x == 0) {
        float t = 0.0f;
        #pragma unroll
        for (int i = 0; i < 16; ++i) t += red[i];
        out0[0] = t * (1.0f / (float)BATCH);
    }
}

// ================= fallback path (bucket gather) =================

__global__ __launch_bounds__(256) void scatter_bucket(const int* __restrict__ labels,
                                                      int* __restrict__ cnt,
                                                      int* __restrict__ bucket) {
    const int i = blockIdx.x * 256 + threadIdx.x;
    const int c = labels[i];
    const int slot = atomicAdd(&cnt[c], 1);
    if (slot < CAP) bucket[c * CAP + slot] = i;
}

__global__ __launch_bounds__(256) void gather_bucket(
        const float* __restrict__ feat, const float* __restrict__ centers,
        const int* __restrict__ cnt, const int* __restrict__ bucket,
        float* __restrict__ outc, float* __restrict__ pB) {
    const int wave = threadIdx.x >> 6;
    const int lane = threadIdx.x & 63;
    const int c    = blockIdx.x * WPB + wave;
    const int n = min(cnt[c], CAP);
    const int myidx = (lane < n) ? bucket[c * CAP + lane] : 0;
    float4 acc = {0.f,0.f,0.f,0.f};
    float fsum2 = 0.f;
    for (int s = 0; s < n; ++s) {
        const int r = __shfl(myidx, s, 64);
        const float4 v = ((const float4*)(feat + (size_t)r * FEAT))[lane];
        float ss = wave_reduce_sum(v.x*v.x + v.y*v.y + v.z*v.z + v.w*v.w);
        const float rinv = 1.0f / fmaxf(sqrtf(ss), EPS);
        acc.x += v.x*rinv; acc.y += v.y*rinv; acc.z += v.z*rinv; acc.w += v.w*rinv;
        fsum2 += ss * rinv * rinv;
    }
    const float4 cv = ((const float4*)(centers + (size_t)c * FEAT))[lane];
    const float fn = (float)n;
    const float w  = 1.0f / (1.0f + fn);
    float4 nc;
    nc.x = cv.x - LAMBDA * (fn*cv.x - acc.x) * w;
    nc.y = cv.y - LAMBDA * (fn*cv.y - acc.y) * w;
    nc.z = cv.z - LAMBDA * (fn*cv.z - acc.z) * w;
    nc.w = cv.w - LAMBDA * (fn*cv.w - acc.w) * w;
    ((float4*)(outc + (size_t)c * FEAT))[lane] = nc;
    float lp = fn * (cv.x*cv.x + cv.y*cv.y + cv.z*cv.z + cv.w*cv.w)
             - 2.0f * (acc.x*cv.x + acc.y*cv.y + acc.z*cv.z + acc.w*cv.w);
    lp = wave_reduce_sum(lp);
    __shared__ float red[WPB];
    if (lane == 0) red[wave] = lp + fsum2;
    __syncthreads();
    if (threadIdx.x == 0)
        pB[blockIdx.x] = red[0] + red[1] + red[2] + red[3];
}

__global__ __launch_bounds__(1024) void finishB(const float* __restrict__ pB,
                                                float* __restrict__ out0) {
    float s = 0.0f;
    for (int i = threadIdx.x; i < NBLK_SS; i += 1024) s += pB[i];
    s = wave_reduce_sum(s);
    __shared__ float red[16];
    const int wave = threadIdx.x >> 6;
    const int lane = threadIdx.x & 63;
    if (lane == 0) red[wave] = s;
    __syncthreads();
    if (threadIdx.x == 0) {
        float t = 0.0f;
        #pragma unroll
        for (int i = 0; i < 16; ++i) t += red[i];
        out0[0] = t * (1.0f / (float)BATCH);
    }
}

extern "C" void kernel_launch(void* const* d_in, const int* in_sizes, int n_in,
                              void* d_out, int out_size, void* d_ws, size_t ws_size,
                              hipStream_t stream) {
    const float* feat    = (const float*)d_in[0];
    const int*   labels  = (const int*)  d_in[1];
    const float* centers = (const float*)d_in[2];
    float* out = (float*)d_out;

    // fast path needs: cnt + cursor + bsum + boff + pA + pB + sIdx + rinvS (~1.6 MB)
    const size_t need_fast =
        ((size_t)NCLASS * 2 + 512 + NBLK_NS + NBLK_SS + (size_t)BATCH * 2) * 4;

    if (ws_size >= need_fast) {
        int*   cnt    = (int*)d_ws;
        int*   cursor = cnt + NCLASS;
        int*   bsum   = cursor + NCLASS;
        int*   boff   = bsum + 256;
        float* pA     = (float*)(boff + 256);
        float* pB     = pA + NBLK_NS;
        int*   sIdx   = (int*)(pB + NBLK_SS);
        float* rinvS  = (float*)(sIdx + BATCH);

        hipMemsetAsync(cnt, 0, NCLASS * sizeof(int), stream);
        histo      <<<BATCH / 256, 256, 0, stream>>>(labels, cnt);
        scan_bsum  <<<NSCAN, 256, 0, stream>>>(cnt, bsum);
        scan_boff  <<<1, 256, 0, stream>>>(bsum, boff);
        scan_final <<<NSCAN, 256, 0, stream>>>(cnt, boff, cursor);
        norm_scatter<<<NBLK_NS, 256, 0, stream>>>(feat, labels, cursor,
                                                  sIdx, rinvS, pA);
        segsum_gather2<<<NBLK_SS, 256, 0, stream>>>(feat, centers, cnt, cursor,
                                                    sIdx, rinvS, out + 1, pB);
        finish<<<1, 1024, 0, stream>>>(pA, pB, out);
    } else {
        int*   cnt    = (int*)d_ws;
        int*   bucket = cnt + NCLASS;
        float* pB     = (float*)(bucket + (size_t)NCLASS * CAP);
        hipMemsetAsync(cnt, 0, NCLASS * sizeof(int), stream);
        scatter_bucket<<<BATCH / 256, 256, 0, stream>>>(labels, cnt, bucket);
        gather_bucket <<<NBLK_SS, 256, 0, stream>>>(feat, centers, cnt, bucket,
                                                    out + 1, pB);
        finishB<<<1, 1024, 0, stream>>>(pB, out);
    }
}